// Round 4
// baseline (11904.036 us; speedup 1.0000x reference)
//
#include <hip/hip_runtime.h>

// ---------------------------------------------------------------------------
// Memory-network forward, fp32-exact (r4: gi-GEMM fused with GRU via
// producer/consumer chunk counters; BM=32 reasoning tiles).
// B=32, MEM=50, SEN=QLEN=20, H=256, 3H=768, VOCAB=100000, HOPS=3, NHEAD=4.
// ---------------------------------------------------------------------------

#define TPB 256
#define NB    32
#define MEMN  50
#define SEN   20
#define VOC   100000
#define SEQEND_TOK 2
#define NGRU  82          // 50 story chains + 32 query chains
#define NTILE 1530        // gi tiles: 255 row-tiles x 6 col-tiles

// ---- workspace layout (float offsets) ----
// gi region [0 .. 25067520) is dead after the fused kernel; later buffers alias.
#define GI_OFF    0
#define KVB_OFF   0            // [1600][512] k|v projections (alias, after gi dead)
#define MB_OFF    819200       // [32][3][256] hop outputs
#define T1_OFF    843776       // [288][768]
#define T2_OFF    1064960      // [288][768]
#define RS_OFF    1286144      // [32][768]
#define WTIH_OFF  25067520     // w_ih^T [256][768]
#define WTHH_OFF  25264128     // w_hh^T [256][768]
#define KVT_OFF   25460736     // [256][512] = [wk^T | wv^T]
#define WQT_OFF   25591808     // [256][256]
#define WOT_OFF   25657344
#define F1T_OFF   25722880
#define F2T_OFF   25788416
#define G1T_OFF   25853952     // g_w1^T [768][768]
#define G2T_OFF   26443776
#define BKV_OFF   27033600     // [512] = bk|bv
#define IDX_OFF   27034112     // 1600 sidx + 32 qidx (ints)
#define SLOT_OFF  27035744     // [32][50][256] memory slots
#define RQ_OFF    27445344     // [32][256] real query
#define CNT_OFF   27453536     // 33 uint chunk counters (zeroed each launch)

// ---------------------------------------------------------------------------
// Setup: transposes to k-major, bias concat, SEQEND index scan, counter zero.
// ---------------------------------------------------------------------------
__global__ void k_setup(const float* __restrict__ w_ih, const float* __restrict__ w_hh,
                        const float* __restrict__ wk,  const float* __restrict__ wv,
                        const float* __restrict__ wq,  const float* __restrict__ wo,
                        const float* __restrict__ f1,  const float* __restrict__ f2,
                        const float* __restrict__ g1,  const float* __restrict__ g2,
                        const float* __restrict__ bk,  const float* __restrict__ bv,
                        const int* __restrict__ story, const int* __restrict__ query,
                        float* __restrict__ ws)
{
  int g = blockIdx.x * TPB + threadIdx.x;
  if (g < 196608) { int j = g >> 8, k = g & 255; ws[WTIH_OFF + k*768 + j] = w_ih[g]; return; }
  g -= 196608;
  if (g < 196608) { int j = g >> 8, k = g & 255; ws[WTHH_OFF + k*768 + j] = w_hh[g]; return; }
  g -= 196608;
  if (g < 65536) { int j = g >> 8, k = g & 255; ws[KVT_OFF + k*512 + j] = wk[g]; return; }
  g -= 65536;
  if (g < 65536) { int j = g >> 8, k = g & 255; ws[KVT_OFF + k*512 + 256 + j] = wv[g]; return; }
  g -= 65536;
  if (g < 65536) { int j = g >> 8, k = g & 255; ws[WQT_OFF + k*256 + j] = wq[g]; return; }
  g -= 65536;
  if (g < 65536) { int j = g >> 8, k = g & 255; ws[WOT_OFF + k*256 + j] = wo[g]; return; }
  g -= 65536;
  if (g < 65536) { int j = g >> 8, k = g & 255; ws[F1T_OFF + k*256 + j] = f1[g]; return; }
  g -= 65536;
  if (g < 65536) { int j = g >> 8, k = g & 255; ws[F2T_OFF + k*256 + j] = f2[g]; return; }
  g -= 65536;
  if (g < 589824) { int j = g / 768, k = g - j*768; ws[G1T_OFF + k*768 + j] = g1[g]; return; }
  g -= 589824;
  if (g < 589824) { int j = g / 768, k = g - j*768; ws[G2T_OFF + k*768 + j] = g2[g]; return; }
  g -= 589824;
  if (g < 512) { ws[BKV_OFF + g] = (g < 256) ? bk[g] : bv[g - 256]; return; }
  g -= 512;
  if (g < 1600) {
    const int* st = story + g * SEN;
    int idx = SEN - 1;
    for (int t = 0; t < SEN; ++t) { if (st[t] == SEQEND_TOK) { idx = t; break; } }
    ((int*)(ws + IDX_OFF))[g] = idx;
    return;
  }
  g -= 1600;
  if (g < 32) {
    const int* qt = query + g * SEN;
    int idx = SEN - 1;
    for (int t = 0; t < SEN; ++t) { if (qt[t] == SEQEND_TOK) { idx = t; break; } }
    ((int*)(ws + IDX_OFF))[1600 + g] = idx;
    return;
  }
  g -= 32;
  if (g < 33) ((unsigned int*)(ws + CNT_OFF))[g] = 0u;   // chunk counters
}

// ---------------------------------------------------------------------------
// Fused kernel. Blocks [0,82): GRU chains. Blocks [82, 82+1530): gi tiles.
//
// Producer tile tix: (mt,nt) = (tix/6, tix%6); computes
//   gi[m0..m0+127][n0..n0+127] = embed[tok[row]] @ w_ih^T + b_ih
// then device-release-increments the chunk counters its rows belong to
// (chunk c = row/1000 for story rows, 32 for query rows).
//
// Consumer (GRU) blocks: lane j owns h[j]; per step computes gates r,z,n.
//   regs : w_r[0:256] + w_z[0:96] + w_z[240:256]           (368 VGPRs)
//   LDS  : w_z[96:240] transposed [j][148] (float4, bank-balanced: 148=4*37,
//          37 mod 8 = 5 coprime with 8 -> 8 lanes cover all 32 banks once)
//   L2   : w_n row (512+j) streamed float4 from ORIGINAL w_hh each step
//          (256 KB/block/step; w_hh 786KB fits each XCD's 4MB L2)
// At each 20-step chunk boundary, block spin-waits (acquire, agent scope)
// until its gi chunk's counter reaches 6 * n_row_tiles(chunk).
// ---------------------------------------------------------------------------
__global__ __launch_bounds__(256, 1) void k_fused(
    float* __restrict__ gi,
    const float* __restrict__ wT, const float* __restrict__ w_hh,
    const float* __restrict__ b_hh, const int* __restrict__ idxI,
    const float* __restrict__ wihT, const float* __restrict__ b_ih,
    const int* __restrict__ tokS, const int* __restrict__ tokQ,
    const float* __restrict__ embed,
    float* __restrict__ slot_out, float* __restrict__ rq_out,
    unsigned int* __restrict__ cnt)
{
  __shared__ __align__(16) char smem[153600];
  const int bid = blockIdx.x;

  if (bid >= NGRU) {
    // ================= producer: one 128x128 gi tile =================
    float* At = (float*)smem;        // [128*33]
    float* Bt = At + 4224;           // [128*33]
    const int tix = bid - NGRU;
    const int mt = tix / 6, nt = tix - mt * 6;
    const int m0 = mt * 128, n0 = nt * 128;
    const int tx = threadIdx.x & 15, ty = threadIdx.x >> 4;
    float acc[8][8] = {};

    for (int k0 = 0; k0 < 256; k0 += 32) {
      for (int idx = threadIdx.x; idx < 4096; idx += 256) {
        int r = idx >> 5, kk = idx & 31;
        int row = m0 + r;
        int tok = (row < 32000) ? tokS[row] : tokQ[row - 32000];
        At[r * 33 + kk] = embed[(size_t)tok * 256 + k0 + kk];
      }
      for (int idx = threadIdx.x; idx < 4096; idx += 256) {
        int jj = idx & 127, kk = idx >> 7;
        Bt[jj * 33 + kk] = wihT[(k0 + kk) * 768 + n0 + jj];
      }
      __syncthreads();
#pragma unroll
      for (int kk = 0; kk < 32; ++kk) {
        float a[8], bb[8];
#pragma unroll
        for (int i = 0; i < 8; ++i) a[i] = At[(i * 16 + ty) * 33 + kk];
#pragma unroll
        for (int i = 0; i < 8; ++i) bb[i] = Bt[(i * 16 + tx) * 33 + kk];
#pragma unroll
        for (int i = 0; i < 8; ++i)
#pragma unroll
          for (int j2 = 0; j2 < 8; ++j2) acc[i][j2] += a[i] * bb[j2];
      }
      __syncthreads();
    }
#pragma unroll
    for (int i = 0; i < 8; ++i) {
      int row = m0 + i * 16 + ty;
#pragma unroll
      for (int j2 = 0; j2 < 8; ++j2) {
        int col = n0 + j2 * 16 + tx;
        gi[(size_t)row * 768 + col] = acc[i][j2] + b_ih[col];
      }
    }
    __threadfence();        // drain stores, device-scope visibility
    __syncthreads();        // all threads' stores fenced
    if (threadIdx.x == 0) {
      const int rLo = m0, rHi = m0 + 127;
      const int cLo = (rLo < 32000) ? (rLo / 1000) : 32;
      const int cHi = (rHi < 32000) ? (rHi / 1000) : 32;
      __hip_atomic_fetch_add(&cnt[cLo], 1u, __ATOMIC_RELEASE, __HIP_MEMORY_SCOPE_AGENT);
      if (cHi != cLo)
        __hip_atomic_fetch_add(&cnt[cHi], 1u, __ATOMIC_RELEASE, __HIP_MEMORY_SCOPE_AGENT);
    }
    return;
  }

  // ================= consumer: GRU chain =================
  const int j = threadIdx.x;
  const int mode = (bid >= MEMN) ? 1 : 0;
  const int blk = mode ? (bid - MEMN) : bid;
  float* __restrict__ cap_out = mode ? rq_out : slot_out;

  float* lwzT = (float*)smem;                           // [256][148]
  float (*hs)[256] = (float (*)[256])(smem + 151552);   // [2][256]

  for (int idx = threadIdx.x; idx < 144 * 256; idx += 256) {
    int i = idx >> 8, jj = idx & 255;                   // coalesced read from wT
    lwzT[jj * 148 + i] = wT[(96 + i) * 768 + 256 + jj];
  }
  float wr[256];
#pragma unroll
  for (int k = 0; k < 256; ++k) wr[k] = wT[k * 768 + j];
  float wz0[96];
#pragma unroll
  for (int k = 0; k < 96; ++k) wz0[k] = wT[k * 768 + 256 + j];
  float wzt[16];
#pragma unroll
  for (int i = 0; i < 16; ++i) wzt[i] = wT[(240 + i) * 768 + 256 + j];

  const float bhr = b_hh[j], bhz = b_hh[256 + j], bhn = b_hh[512 + j];
  const float* __restrict__ whn = w_hh + (size_t)(512 + j) * 256;  // w_n row j
  const float* __restrict__ lz = lwzT + j * 148;

  float hold = 0.f;
  hs[0][j] = 0.f; hs[1][j] = 0.f;
  __syncthreads();

  const int steps = mode ? SEN : (NB * SEN);
  int buf = 0, b = 0, t = 0, cs = 0;

#pragma unroll 1
  for (int s = 0; s < steps; ++s) {
    if (t == 0) {
      // wait until this chunk's gi rows are published (6 col-tiles each)
      if (threadIdx.x == 0) {
        const int c   = mode ? 32 : b;
        const int rLo = mode ? 32000 : b * 1000;
        const int rHi = mode ? 32639 : b * 1000 + 999;
        const unsigned expv = 6u * (unsigned)(rHi / 128 - rLo / 128 + 1);
        while (__hip_atomic_load(&cnt[c], __ATOMIC_ACQUIRE, __HIP_MEMORY_SCOPE_AGENT) < expv)
          __builtin_amdgcn_s_sleep(16);
      }
      __syncthreads();
      cs = idxI[mode ? (1600 + blk) : (b * MEMN + blk)];
    }
    const int row = mode ? (32000 + blk * SEN + t) : (b * 1000 + blk * SEN + t);
    const float* g = gi + (size_t)row * 768;
    float gr = g[j], gz = g[j + 256], gn = g[j + 512];
    const float4* hc4 = (const float4*)hs[buf];
    float dr = 0.f, dz = 0.f, dn = 0.f;

    // merged dot loop over 16 chunks of 16: r (regs), z (regs/LDS), n (L2 x4)
#pragma unroll
    for (int c = 0; c < 16; ++c) {
      const float4* wn4 = (const float4*)(whn + c * 16);
      float4 w0 = wn4[0], w1 = wn4[1], w2 = wn4[2], w3 = wn4[3];
      float4 h0 = hc4[c * 4 + 0], h1 = hc4[c * 4 + 1];
      float4 h2 = hc4[c * 4 + 2], h3 = hc4[c * 4 + 3];

      dn += w0.x*h0.x + w0.y*h0.y + w0.z*h0.z + w0.w*h0.w
          + w1.x*h1.x + w1.y*h1.y + w1.z*h1.z + w1.w*h1.w
          + w2.x*h2.x + w2.y*h2.y + w2.z*h2.z + w2.w*h2.w
          + w3.x*h3.x + w3.y*h3.y + w3.z*h3.z + w3.w*h3.w;

      const int k0 = c * 16;
      dr += wr[k0+ 0]*h0.x + wr[k0+ 1]*h0.y + wr[k0+ 2]*h0.z + wr[k0+ 3]*h0.w
          + wr[k0+ 4]*h1.x + wr[k0+ 5]*h1.y + wr[k0+ 6]*h1.z + wr[k0+ 7]*h1.w
          + wr[k0+ 8]*h2.x + wr[k0+ 9]*h2.y + wr[k0+10]*h2.z + wr[k0+11]*h2.w
          + wr[k0+12]*h3.x + wr[k0+13]*h3.y + wr[k0+14]*h3.z + wr[k0+15]*h3.w;

      if (c < 6) {
        dz += wz0[k0+ 0]*h0.x + wz0[k0+ 1]*h0.y + wz0[k0+ 2]*h0.z + wz0[k0+ 3]*h0.w
            + wz0[k0+ 4]*h1.x + wz0[k0+ 5]*h1.y + wz0[k0+ 6]*h1.z + wz0[k0+ 7]*h1.w
            + wz0[k0+ 8]*h2.x + wz0[k0+ 9]*h2.y + wz0[k0+10]*h2.z + wz0[k0+11]*h2.w
            + wz0[k0+12]*h3.x + wz0[k0+13]*h3.y + wz0[k0+14]*h3.z + wz0[k0+15]*h3.w;
      } else if (c < 15) {
        const float4* z4 = (const float4*)(lz + (c - 6) * 16);
        float4 z0 = z4[0], z1 = z4[1], z2 = z4[2], z3 = z4[3];
        dz += z0.x*h0.x + z0.y*h0.y + z0.z*h0.z + z0.w*h0.w
            + z1.x*h1.x + z1.y*h1.y + z1.z*h1.z + z1.w*h1.w
            + z2.x*h2.x + z2.y*h2.y + z2.z*h2.z + z2.w*h2.w
            + z3.x*h3.x + z3.y*h3.y + z3.z*h3.z + z3.w*h3.w;
      } else {
        dz += wzt[ 0]*h0.x + wzt[ 1]*h0.y + wzt[ 2]*h0.z + wzt[ 3]*h0.w
            + wzt[ 4]*h1.x + wzt[ 5]*h1.y + wzt[ 6]*h1.z + wzt[ 7]*h1.w
            + wzt[ 8]*h2.x + wzt[ 9]*h2.y + wzt[10]*h2.z + wzt[11]*h2.w
            + wzt[12]*h3.x + wzt[13]*h3.y + wzt[14]*h3.z + wzt[15]*h3.w;
      }
    }

    float rg = 1.f / (1.f + __expf(-(gr + dr + bhr)));
    float zg = 1.f / (1.f + __expf(-(gz + dz + bhz)));
    float xn = gn + rg * (dn + bhn);
    xn = fminf(fmaxf(xn, -15.f), 15.f);
    float e2 = __expf(-2.f * xn);
    float ng = (1.f - e2) / (1.f + e2);
    float hnew = (1.f - zg) * ng + zg * hold;

    hs[buf ^ 1][j] = hnew;
    if (t == cs) cap_out[(mode ? blk : (b * MEMN + blk)) * 256 + j] = hnew;
    hold = hnew;
    buf ^= 1;
    if (++t == SEN) { t = 0; ++b; }
    __syncthreads();
  }
}

// ---------------------------------------------------------------------------
// Generic fp32 tiled GEMM: C[M][N] = A[M][K] @ B(k-major [K][N]) + bias.
// BM x 128 tile, BK=32, 256 threads, (BM/16) x 8 per-thread tile.
// MODE 0: plain A; MODE 2: reason-combined gather.
// ---------------------------------------------------------------------------
template<int MODE, int BM>
__global__ __launch_bounds__(256) void k_gemm(
    const float* __restrict__ A, const float* __restrict__ B,
    const float* __restrict__ bias, float* __restrict__ C,
    int M, int N, int K, int relu,
    const float* __restrict__ mbp, const float* __restrict__ rqp)
{
  __shared__ float At[BM * 33];
  __shared__ float Bt[128 * 33];
  constexpr int R = BM / 16;
  const int m0 = blockIdx.x * BM, n0 = blockIdx.y * 128;
  const int tx = threadIdx.x & 15, ty = threadIdx.x >> 4;
  float acc[R][8] = {};

  for (int k0 = 0; k0 < K; k0 += 32) {
    for (int idx = threadIdx.x; idx < BM * 32; idx += 256) {
      int r = idx >> 5, kk = idx & 31;
      int row = m0 + r, kg = k0 + kk;
      float v = 0.f;
      if (MODE == 2) {
        if (row < 288) {
          int b = row / 9, p = row - b * 9;
          v = (kg < 256) ? mbp[(b*3 + (p % 3))*256 + kg]
            : (kg < 512) ? mbp[(b*3 + (p / 3))*256 + (kg - 256)]
                         : rqp[b*256 + (kg - 512)];
        }
      } else {
        if (row < M) v = A[(size_t)row * K + kg];
      }
      At[r * 33 + kk] = v;
    }
    for (int idx = threadIdx.x; idx < 4096; idx += 256) {
      int jj = idx & 127, kk = idx >> 7;
      Bt[jj * 33 + kk] = B[(k0 + kk) * N + n0 + jj];
    }
    __syncthreads();
#pragma unroll
    for (int kk = 0; kk < 32; ++kk) {
      float a[R], bb[8];
#pragma unroll
      for (int i = 0; i < R; ++i) a[i] = At[(i * 16 + ty) * 33 + kk];
#pragma unroll
      for (int i = 0; i < 8; ++i) bb[i] = Bt[(i * 16 + tx) * 33 + kk];
#pragma unroll
      for (int i = 0; i < R; ++i)
#pragma unroll
        for (int j2 = 0; j2 < 8; ++j2) acc[i][j2] += a[i] * bb[j2];
    }
    __syncthreads();
  }
#pragma unroll
  for (int i = 0; i < R; ++i) {
    int row = m0 + i * 16 + ty;
    if (row >= M) continue;
#pragma unroll
    for (int j2 = 0; j2 < 8; ++j2) {
      int col = n0 + j2 * 16 + tx;
      float v = acc[i][j2] + bias[col];
      if (relu) v = fmaxf(v, 0.f);
      C[(size_t)row * N + col] = v;
    }
  }
}

// ---------------------------------------------------------------------------
// Multi-hop attention, one block per batch element. k/v staged in LDS
// (stride 259 -> conflict-light). Wave w handles head w for softmax.
// ---------------------------------------------------------------------------
__device__ __forceinline__ float gemv256(const float* __restrict__ WT,
                                         const float* __restrict__ xs, int j)
{
  float acc = 0.f;
#pragma unroll 64
  for (int k = 0; k < 256; ++k) acc += xs[k] * WT[k * 256 + j];
  return acc;
}

__global__ __launch_bounds__(256) void k_hops(
    const float* __restrict__ rq, const float* __restrict__ kvb,
    const float* __restrict__ wqT, const float* __restrict__ bq,
    const float* __restrict__ woT, const float* __restrict__ bo,
    const float* __restrict__ f1T, const float* __restrict__ fb1,
    const float* __restrict__ f2T, const float* __restrict__ fb2,
    float* __restrict__ mb)
{
  const int b = blockIdx.x, j = threadIdx.x;
  __shared__ float lk[50 * 259];
  __shared__ float lv[50 * 259];
  __shared__ float xs[256], tb[256], qs[256], avs[256], ob[256], asc[256];

  for (int idx = j; idx < 12800; idx += 256) {
    int m = idx >> 8, d = idx & 255;
    lk[m * 259 + d] = kvb[(b * MEMN + m) * 512 + d];
    lv[m * 259 + d] = kvb[(b * MEMN + m) * 512 + 256 + d];
  }
  xs[j] = rq[b * 256 + j];
  __syncthreads();

  float v = fmaxf(gemv256(f1T, xs, j) + fb1[j], 0.f);
  __syncthreads(); tb[j] = v; __syncthreads();
  v = gemv256(f2T, tb, j) + fb2[j];
  __syncthreads(); xs[j] = v; __syncthreads();

  for (int hop = 0; hop < 3; ++hop) {
    v = gemv256(wqT, xs, j) + bq[j];
    __syncthreads(); qs[j] = v; __syncthreads();

    const int w = j >> 6, l = j & 63;
    float sc = -1e30f;
    if (l < MEMN) {
      sc = 0.f;
#pragma unroll 16
      for (int d = 0; d < 64; ++d) sc += qs[w * 64 + d] * lk[l * 259 + w * 64 + d];
      sc *= 0.125f;  // 1/sqrt(dk=64)
    }
    float mx = sc;
#pragma unroll
    for (int off = 32; off > 0; off >>= 1) mx = fmaxf(mx, __shfl_xor(mx, off));
    float e = (l < MEMN) ? __expf(sc - mx) : 0.f;
    float sm = e;
#pragma unroll
    for (int off = 32; off > 0; off >>= 1) sm += __shfl_xor(sm, off);
    float a = e / sm;
    __syncthreads(); asc[j] = a; __syncthreads();

    float av = 0.f;
#pragma unroll 10
    for (int m = 0; m < MEMN; ++m) av += asc[w * 64 + m] * lv[m * 259 + w * 64 + l];
    __syncthreads(); avs[j] = av; __syncthreads();

    v = gemv256(woT, avs, j) + bo[j];
    mb[(b * 3 + hop) * 256 + j] = v;
    if (hop < 2) {
      __syncthreads(); ob[j] = v; __syncthreads();
      v = fmaxf(gemv256(f1T, ob, j) + fb1[j], 0.f);
      __syncthreads(); tb[j] = v; __syncthreads();
      v = gemv256(f2T, tb, j) + fb2[j];
      __syncthreads(); xs[j] = v; __syncthreads();
    }
  }
}

// reasoning[b][j] = sum_p relu(t2)[b*9+p][j]  (t2 already relu'd)
__global__ void k_rsum(const float* __restrict__ t2, float* __restrict__ rs)
{
  int gid = blockIdx.x * TPB + threadIdx.x;
  int b = gid / 768, jj = gid - b * 768;
  float acc = 0.f;
#pragma unroll
  for (int p = 0; p < 9; ++p) acc += t2[(b * 9 + p) * 768 + jj];
  rs[b * 768 + jj] = acc;
}

// out[32][100000] = reasoning @ v_w^T. 64 vocab cols per block, K chunked 128.
// float4 staging, LDS pad 132 (16B-aligned rows).
__global__ __launch_bounds__(256) void k_vocab(const float* __restrict__ rs,
                                               const float* __restrict__ vw,
                                               float* __restrict__ out)
{
  __shared__ float vt[64 * 132];
  __shared__ float rt[32 * 132];
  const int c0 = blockIdx.x * 64;
  const int tx = threadIdx.x & 15, ty = threadIdx.x >> 4;
  float acc[2][4] = {{0.f,0.f,0.f,0.f},{0.f,0.f,0.f,0.f}};

  for (int k0 = 0; k0 < 768; k0 += 128) {
    for (int idx = threadIdx.x; idx < 2048; idx += 256) {
      int r = idx >> 5, q = idx & 31;
      int col = c0 + r;
      float4 v4 = make_float4(0.f, 0.f, 0.f, 0.f);
      if (col < VOC) v4 = ((const float4*)(vw + (size_t)col * 768 + k0))[q];
      *(float4*)&vt[r * 132 + q * 4] = v4;
    }
    for (int idx = threadIdx.x; idx < 1024; idx += 256) {
      int r = idx >> 5, q = idx & 31;
      float4 v4 = ((const float4*)(rs + r * 768 + k0))[q];
      *(float4*)&rt[r * 132 + q * 4] = v4;
    }
    __syncthreads();
#pragma unroll 4
    for (int kk = 0; kk < 128; ++kk) {
      float a0 = rt[(ty * 2 + 0) * 132 + kk];
      float a1 = rt[(ty * 2 + 1) * 132 + kk];
#pragma unroll
      for (int cc = 0; cc < 4; ++cc) {
        float bv_ = vt[(tx + cc * 16) * 132 + kk];
        acc[0][cc] += a0 * bv_;
        acc[1][cc] += a1 * bv_;
      }
    }
    __syncthreads();
  }
#pragma unroll
  for (int rr = 0; rr < 2; ++rr)
#pragma unroll
    for (int cc = 0; cc < 4; ++cc) {
      int c = c0 + tx + cc * 16;
      if (c < VOC) out[(ty * 2 + rr) * VOC + c] = acc[rr][cc];
    }
}

// ---------------------------------------------------------------------------
extern "C" void kernel_launch(void* const* d_in, const int* in_sizes, int n_in,
                              void* d_out, int out_size, void* d_ws, size_t ws_size,
                              hipStream_t stream)
{
  const int*   story = (const int*)d_in[0];
  const int*   query = (const int*)d_in[1];
  const float* embed = (const float*)d_in[2];
  const float* w_ih  = (const float*)d_in[3];
  const float* w_hh  = (const float*)d_in[4];
  const float* b_ih  = (const float*)d_in[5];
  const float* b_hh  = (const float*)d_in[6];
  const float* ft_w1 = (const float*)d_in[7];
  const float* ft_b1 = (const float*)d_in[8];
  const float* ft_w2 = (const float*)d_in[9];
  const float* ft_b2 = (const float*)d_in[10];
  const float* wq    = (const float*)d_in[11];
  const float* bq    = (const float*)d_in[12];
  const float* wk    = (const float*)d_in[13];
  const float* bk    = (const float*)d_in[14];
  const float* wv    = (const float*)d_in[15];
  const float* bv    = (const float*)d_in[16];
  const float* wo    = (const float*)d_in[17];
  const float* bo    = (const float*)d_in[18];
  const float* g_w1  = (const float*)d_in[19];
  const float* g_b1  = (const float*)d_in[20];
  const float* g_w2  = (const float*)d_in[21];
  const float* g_b2  = (const float*)d_in[22];
  const float* v_w   = (const float*)d_in[23];
  float* out = (float*)d_out;
  float* ws  = (float*)d_ws;

  // 1) transposes / biases / seqend indices / counter zero
  k_setup<<<7689, TPB, 0, stream>>>(w_ih, w_hh, wk, wv, wq, wo, ft_w1, ft_w2,
                                    g_w1, g_w2, bk, bv, story, query, ws);
  // 2) fused: gi producer tiles (blocks 82..1611) + GRU chains (blocks 0..81)
  k_fused<<<NGRU + NTILE, TPB, 0, stream>>>(
      ws + GI_OFF, ws + WTHH_OFF, w_hh, b_hh, (const int*)(ws + IDX_OFF),
      ws + WTIH_OFF, b_ih, story, query, embed,
      ws + SLOT_OFF, ws + RQ_OFF, (unsigned int*)(ws + CNT_OFF));
  // 3) k/v projections: [1600][512] = slots @ [wk^T|wv^T] + [bk|bv]
  k_gemm<0,128><<<dim3(13, 4), TPB, 0, stream>>>(
      ws + SLOT_OFF, ws + KVT_OFF, ws + BKV_OFF, ws + KVB_OFF, 1600, 512, 256, 0,
      nullptr, nullptr);
  // 4) 3 attention hops + f_t chain
  k_hops<<<NB, TPB, 0, stream>>>(ws + RQ_OFF, ws + KVB_OFF,
                                 ws + WQT_OFF, bq, ws + WOT_OFF, bo,
                                 ws + F1T_OFF, ft_b1, ws + F2T_OFF, ft_b2,
                                 ws + MB_OFF);
  // 5) reasoning layer 1: relu(comb @ g_w1^T + b1), M=288 (32-row tiles)
  k_gemm<2,32><<<dim3(9, 6), TPB, 0, stream>>>(
      nullptr, ws + G1T_OFF, g_b1, ws + T1_OFF, 288, 768, 768, 1,
      ws + MB_OFF, ws + RQ_OFF);
  // 6) reasoning layer 2: relu(t1 @ g_w2^T + b2)
  k_gemm<0,32><<<dim3(9, 6), TPB, 0, stream>>>(
      ws + T1_OFF, ws + G2T_OFF, g_b2, ws + T2_OFF, 288, 768, 768, 1,
      nullptr, nullptr);
  // 7) sum over 9 pairs
  k_rsum<<<96, TPB, 0, stream>>>(ws + T2_OFF, ws + RS_OFF);
  // 8) logits = reasoning @ v_w^T
  k_vocab<<<(VOC + 63) / 64, TPB, 0, stream>>>(ws + RS_OFF, v_w, out);
}

// Round 5
// 9358.783 us; speedup vs baseline: 1.2720x; 1.2720x over previous
//
#include <hip/hip_runtime.h>

// ---------------------------------------------------------------------------
// Memory-network forward, fp32-exact (r5: GRU re-partitioned to 1024 threads,
// 192 weight-VGPRs/lane max -- fixes the r4 spill catastrophe).
// B=32, MEM=50, SEN=QLEN=20, H=256, 3H=768, VOCAB=100000, HOPS=3, NHEAD=4.
// ---------------------------------------------------------------------------

#define TPB 256
#define NB    32
#define MEMN  50
#define SEN   20
#define VOC   100000
#define SEQEND_TOK 2
#define NGRU  82          // 50 story chains + 32 query chains
#define NTILE 1530        // gi tiles: 255 row-tiles x 6 col-tiles

// ---- workspace layout (float offsets) ----
#define GI_OFF    0
#define KVB_OFF   0            // [1600][512] k|v projections (alias, after gi dead)
#define MB_OFF    819200       // [32][3][256] hop outputs
#define T1_OFF    843776       // [288][768]
#define T2_OFF    1064960      // [288][768]
#define RS_OFF    1286144      // [32][768]
#define WTIH_OFF  25067520     // w_ih^T [256][768]
#define WTHH_OFF  25264128     // w_hh^T [256][768] (unused by GRU now; kept)
#define KVT_OFF   25460736     // [256][512] = [wk^T | wv^T]
#define WQT_OFF   25591808     // [256][256]
#define WOT_OFF   25657344
#define F1T_OFF   25722880
#define F2T_OFF   25788416
#define G1T_OFF   25853952     // g_w1^T [768][768]
#define G2T_OFF   26443776
#define BKV_OFF   27033600     // [512] = bk|bv
#define IDX_OFF   27034112     // 1600 sidx + 32 qidx (ints)
#define SLOT_OFF  27035744     // [32][50][256] memory slots
#define RQ_OFF    27445344     // [32][256] real query
#define CNT_OFF   27453536     // 33 uint chunk counters (zeroed each launch)

// ---------------------------------------------------------------------------
// Setup: transposes to k-major, bias concat, SEQEND index scan, counter zero.
// ---------------------------------------------------------------------------
__global__ void k_setup(const float* __restrict__ w_ih, const float* __restrict__ w_hh,
                        const float* __restrict__ wk,  const float* __restrict__ wv,
                        const float* __restrict__ wq,  const float* __restrict__ wo,
                        const float* __restrict__ f1,  const float* __restrict__ f2,
                        const float* __restrict__ g1,  const float* __restrict__ g2,
                        const float* __restrict__ bk,  const float* __restrict__ bv,
                        const int* __restrict__ story, const int* __restrict__ query,
                        float* __restrict__ ws)
{
  int g = blockIdx.x * TPB + threadIdx.x;
  if (g < 196608) { int j = g >> 8, k = g & 255; ws[WTIH_OFF + k*768 + j] = w_ih[g]; return; }
  g -= 196608;
  if (g < 196608) { int j = g >> 8, k = g & 255; ws[WTHH_OFF + k*768 + j] = w_hh[g]; return; }
  g -= 196608;
  if (g < 65536) { int j = g >> 8, k = g & 255; ws[KVT_OFF + k*512 + j] = wk[g]; return; }
  g -= 65536;
  if (g < 65536) { int j = g >> 8, k = g & 255; ws[KVT_OFF + k*512 + 256 + j] = wv[g]; return; }
  g -= 65536;
  if (g < 65536) { int j = g >> 8, k = g & 255; ws[WQT_OFF + k*256 + j] = wq[g]; return; }
  g -= 65536;
  if (g < 65536) { int j = g >> 8, k = g & 255; ws[WOT_OFF + k*256 + j] = wo[g]; return; }
  g -= 65536;
  if (g < 65536) { int j = g >> 8, k = g & 255; ws[F1T_OFF + k*256 + j] = f1[g]; return; }
  g -= 65536;
  if (g < 65536) { int j = g >> 8, k = g & 255; ws[F2T_OFF + k*256 + j] = f2[g]; return; }
  g -= 65536;
  if (g < 589824) { int j = g / 768, k = g - j*768; ws[G1T_OFF + k*768 + j] = g1[g]; return; }
  g -= 589824;
  if (g < 589824) { int j = g / 768, k = g - j*768; ws[G2T_OFF + k*768 + j] = g2[g]; return; }
  g -= 589824;
  if (g < 512) { ws[BKV_OFF + g] = (g < 256) ? bk[g] : bv[g - 256]; return; }
  g -= 512;
  if (g < 1600) {
    const int* st = story + g * SEN;
    int idx = SEN - 1;
    for (int t = 0; t < SEN; ++t) { if (st[t] == SEQEND_TOK) { idx = t; break; } }
    ((int*)(ws + IDX_OFF))[g] = idx;
    return;
  }
  g -= 1600;
  if (g < 32) {
    const int* qt = query + g * SEN;
    int idx = SEN - 1;
    for (int t = 0; t < SEN; ++t) { if (qt[t] == SEQEND_TOK) { idx = t; break; } }
    ((int*)(ws + IDX_OFF))[1600 + g] = idx;
    return;
  }
  g -= 32;
  if (g < 33) ((unsigned int*)(ws + CNT_OFF))[g] = 0u;   // chunk counters
}

// ---------------------------------------------------------------------------
// Fused kernel, 1024 threads/block. Blocks [0,82): GRU chains (consumers).
// Blocks [82, 82+1530): gi 128x128 tiles (producers).
//
// Consumer layout (the r4 fix -- max 192 weight VGPRs per lane, NO spill):
//   threads 0..767   : gate-row t, cols [0,192)   -> 48 float4 weights in VGPRs
//   threads 768..1023: rows {u, u+256, u+512}, cols [192,256) -> 48 float4
//   h[256] in LDS; every h read is a same-address wave BROADCAST (free).
//   Partial sums meet in LDS (tot[768], ptail[768]); threads 0..255 combine
//   gates (sigmoid/tanh), keep h_old in a register, write h back to LDS.
//   2 barriers/step. VALU floor: 196K MAC / 128 FMA-per-cy-CU = 1536 cy/step.
// LDS padded to 112 KB -> exactly 1 block/CU (no VALU sharing with producers).
// ---------------------------------------------------------------------------
__global__ __launch_bounds__(1024, 1) void k_fused(
    float* __restrict__ gi,
    const float* __restrict__ w_hh, const float* __restrict__ b_hh,
    const int* __restrict__ idxI,
    const float* __restrict__ wihT, const float* __restrict__ b_ih,
    const int* __restrict__ tokS, const int* __restrict__ tokQ,
    const float* __restrict__ embed,
    float* __restrict__ slot_out, float* __restrict__ rq_out,
    unsigned int* __restrict__ cnt)
{
  __shared__ __align__(16) char smem[114688];   // 112 KB -> 1 block/CU
  const int bid = blockIdx.x;
  const int tid = threadIdx.x;

  if (bid >= NGRU) {
    // ================= producer: one 128x128 gi tile =================
    float* At = (float*)smem;        // [128*33]
    float* Bt = At + 4224;           // [128*33]
    const int tix = bid - NGRU;
    const int mt = tix / 6, nt = tix - mt * 6;
    const int m0 = mt * 128, n0 = nt * 128;
    const int tx = tid & 15, ty = (tid >> 4) & 63;
    float acc[2][8] = {};

    for (int k0 = 0; k0 < 256; k0 += 32) {
      for (int idx = tid; idx < 4096; idx += 1024) {
        int r = idx >> 5, kk = idx & 31;
        int row = m0 + r;
        int tok = (row < 32000) ? tokS[row] : tokQ[row - 32000];
        At[r * 33 + kk] = embed[(size_t)tok * 256 + k0 + kk];
      }
      for (int idx = tid; idx < 4096; idx += 1024) {
        int jj = idx & 127, kk = idx >> 7;
        Bt[jj * 33 + kk] = wihT[(k0 + kk) * 768 + n0 + jj];
      }
      __syncthreads();
#pragma unroll
      for (int kk = 0; kk < 32; ++kk) {
        float a0 = At[ty * 33 + kk], a1 = At[(64 + ty) * 33 + kk];
        float bb[8];
#pragma unroll
        for (int i = 0; i < 8; ++i) bb[i] = Bt[(i * 16 + tx) * 33 + kk];
#pragma unroll
        for (int i = 0; i < 8; ++i) { acc[0][i] += a0 * bb[i]; acc[1][i] += a1 * bb[i]; }
      }
      __syncthreads();
    }
#pragma unroll
    for (int i = 0; i < 2; ++i) {
      int row = m0 + i * 64 + ty;
#pragma unroll
      for (int j2 = 0; j2 < 8; ++j2) {
        int col = n0 + j2 * 16 + tx;
        gi[(size_t)row * 768 + col] = acc[i][j2] + b_ih[col];
      }
    }
    __threadfence();
    __syncthreads();
    if (tid == 0) {
      const int rLo = m0, rHi = m0 + 127;
      const int cLo = (rLo < 32000) ? (rLo / 1000) : 32;
      const int cHi = (rHi < 32000) ? (rHi / 1000) : 32;
      __hip_atomic_fetch_add(&cnt[cLo], 1u, __ATOMIC_RELEASE, __HIP_MEMORY_SCOPE_AGENT);
      if (cHi != cLo)
        __hip_atomic_fetch_add(&cnt[cHi], 1u, __ATOMIC_RELEASE, __HIP_MEMORY_SCOPE_AGENT);
    }
    return;
  }

  // ================= consumer: GRU chain =================
  const int mode = (bid >= MEMN) ? 1 : 0;
  const int blk = mode ? (bid - MEMN) : bid;
  float* __restrict__ cap_out = mode ? rq_out : slot_out;

  float* tot   = (float*)smem;        // [768]
  float* ptail = tot + 768;           // [768]
  float* hs    = ptail + 768;         // [256]

  // ---- load weights into registers (<=192 VGPRs per lane) ----
  float4 w4[48];
  if (tid < 768) {
    const float* wrow = w_hh + (size_t)tid * 256;
#pragma unroll
    for (int q = 0; q < 48; ++q) w4[q] = ((const float4*)wrow)[q];
  } else {
    const int u = tid - 768;
#pragma unroll
    for (int rr = 0; rr < 3; ++rr) {
      const float* wrow = w_hh + (size_t)(u + rr * 256) * 256 + 192;
#pragma unroll
      for (int q = 0; q < 16; ++q) w4[rr * 16 + q] = ((const float4*)wrow)[q];
    }
  }
  const float bh = (tid < 768) ? b_hh[tid] : 0.f;

  if (tid < 256) hs[tid] = 0.f;
  float hold = 0.f;
  __syncthreads();

  const int steps = mode ? SEN : (NB * SEN);
  int b = 0, t = 0, cs = 0;

#pragma unroll 1
  for (int s = 0; s < steps; ++s) {
    if (t == 0) {
      if (tid == 0) {
        const int c   = mode ? 32 : b;
        const int rLo = mode ? 32000 : b * 1000;
        const int rHi = mode ? 32639 : b * 1000 + 999;
        const unsigned expv = 6u * (unsigned)(rHi / 128 - rLo / 128 + 1);
        while (__hip_atomic_load(&cnt[c], __ATOMIC_ACQUIRE, __HIP_MEMORY_SCOPE_AGENT) < expv)
          __builtin_amdgcn_s_sleep(16);
      }
      __syncthreads();
      cs = idxI[mode ? (1600 + blk) : (b * MEMN + blk)];
    }
    const int srow = mode ? (32000 + blk * SEN + t) : (b * 1000 + blk * SEN + t);

    if (tid < 768) {
      // rows: full dot over cols [0,192); h reads broadcast from LDS
      float dot = 0.f;
#pragma unroll
      for (int q = 0; q < 48; ++q) {
        float4 h4 = ((const float4*)hs)[q];
        dot += w4[q].x * h4.x + w4[q].y * h4.y + w4[q].z * h4.z + w4[q].w * h4.w;
      }
      float v = dot + bh;
      if (tid < 512) v += gi[(size_t)srow * 768 + tid];   // r,z rows add gi here
      tot[tid] = v;
    } else {
      // tail: cols [192,256) of rows u, u+256, u+512
      const int u = tid - 768;
      float p0 = 0.f, p1 = 0.f, p2 = 0.f;
      const float4* ht = (const float4*)(hs + 192);
#pragma unroll
      for (int q = 0; q < 16; ++q) {
        float4 h4 = ht[q];
        p0 += w4[q     ].x * h4.x + w4[q     ].y * h4.y + w4[q     ].z * h4.z + w4[q     ].w * h4.w;
        p1 += w4[16 + q].x * h4.x + w4[16 + q].y * h4.y + w4[16 + q].z * h4.z + w4[16 + q].w * h4.w;
        p2 += w4[32 + q].x * h4.x + w4[32 + q].y * h4.y + w4[32 + q].z * h4.z + w4[32 + q].w * h4.w;
      }
      ptail[u] = p0; ptail[u + 256] = p1; ptail[u + 512] = p2;
    }
    __syncthreads();

    if (tid < 256) {
      float Sr = tot[tid]       + ptail[tid];
      float Sz = tot[tid + 256] + ptail[tid + 256];
      float Sn = tot[tid + 512] + ptail[tid + 512];   // = h.w_n + b_hh_n
      float gn = gi[(size_t)srow * 768 + 512 + tid];
      float rg = 1.f / (1.f + __expf(-Sr));
      float zg = 1.f / (1.f + __expf(-Sz));
      float xn = gn + rg * Sn;
      xn = fminf(fmaxf(xn, -15.f), 15.f);
      float e2 = __expf(-2.f * xn);
      float ng = (1.f - e2) / (1.f + e2);
      float hnew = (1.f - zg) * ng + zg * hold;
      hs[tid] = hnew;
      if (t == cs) cap_out[(mode ? blk : (b * MEMN + blk)) * 256 + tid] = hnew;
      hold = hnew;
    }
    __syncthreads();
    if (++t == SEN) { t = 0; ++b; }
  }
}

// ---------------------------------------------------------------------------
// Generic fp32 tiled GEMM: C[M][N] = A[M][K] @ B(k-major [K][N]) + bias.
// BM x 128 tile, BK=32, 256 threads. MODE 0: plain A; MODE 2: reason gather.
// ---------------------------------------------------------------------------
template<int MODE, int BM>
__global__ __launch_bounds__(256) void k_gemm(
    const float* __restrict__ A, const float* __restrict__ B,
    const float* __restrict__ bias, float* __restrict__ C,
    int M, int N, int K, int relu,
    const float* __restrict__ mbp, const float* __restrict__ rqp)
{
  __shared__ float At[BM * 33];
  __shared__ float Bt[128 * 33];
  constexpr int R = BM / 16;
  const int m0 = blockIdx.x * BM, n0 = blockIdx.y * 128;
  const int tx = threadIdx.x & 15, ty = threadIdx.x >> 4;
  float acc[R][8] = {};

  for (int k0 = 0; k0 < K; k0 += 32) {
    for (int idx = threadIdx.x; idx < BM * 32; idx += 256) {
      int r = idx >> 5, kk = idx & 31;
      int row = m0 + r, kg = k0 + kk;
      float v = 0.f;
      if (MODE == 2) {
        if (row < 288) {
          int b = row / 9, p = row - b * 9;
          v = (kg < 256) ? mbp[(b*3 + (p % 3))*256 + kg]
            : (kg < 512) ? mbp[(b*3 + (p / 3))*256 + (kg - 256)]
                         : rqp[b*256 + (kg - 512)];
        }
      } else {
        if (row < M) v = A[(size_t)row * K + kg];
      }
      At[r * 33 + kk] = v;
    }
    for (int idx = threadIdx.x; idx < 4096; idx += 256) {
      int jj = idx & 127, kk = idx >> 7;
      Bt[jj * 33 + kk] = B[(k0 + kk) * N + n0 + jj];
    }
    __syncthreads();
#pragma unroll
    for (int kk = 0; kk < 32; ++kk) {
      float a[R], bb[8];
#pragma unroll
      for (int i = 0; i < R; ++i) a[i] = At[(i * 16 + ty) * 33 + kk];
#pragma unroll
      for (int i = 0; i < 8; ++i) bb[i] = Bt[(i * 16 + tx) * 33 + kk];
#pragma unroll
      for (int i = 0; i < R; ++i)
#pragma unroll
        for (int j2 = 0; j2 < 8; ++j2) acc[i][j2] += a[i] * bb[j2];
    }
    __syncthreads();
  }
#pragma unroll
  for (int i = 0; i < R; ++i) {
    int row = m0 + i * 16 + ty;
    if (row >= M) continue;
#pragma unroll
    for (int j2 = 0; j2 < 8; ++j2) {
      int col = n0 + j2 * 16 + tx;
      float v = acc[i][j2] + bias[col];
      if (relu) v = fmaxf(v, 0.f);
      C[(size_t)row * N + col] = v;
    }
  }
}

// ---------------------------------------------------------------------------
// Multi-hop attention, one block per batch element.
// ---------------------------------------------------------------------------
__device__ __forceinline__ float gemv256(const float* __restrict__ WT,
                                         const float* __restrict__ xs, int j)
{
  float acc = 0.f;
#pragma unroll 64
  for (int k = 0; k < 256; ++k) acc += xs[k] * WT[k * 256 + j];
  return acc;
}

__global__ __launch_bounds__(256) void k_hops(
    const float* __restrict__ rq, const float* __restrict__ kvb,
    const float* __restrict__ wqT, const float* __restrict__ bq,
    const float* __restrict__ woT, const float* __restrict__ bo,
    const float* __restrict__ f1T, const float* __restrict__ fb1,
    const float* __restrict__ f2T, const float* __restrict__ fb2,
    float* __restrict__ mb)
{
  const int b = blockIdx.x, j = threadIdx.x;
  __shared__ float lk[50 * 259];
  __shared__ float lv[50 * 259];
  __shared__ float xs[256], tb[256], qs[256], avs[256], ob[256], asc[256];

  for (int idx = j; idx < 12800; idx += 256) {
    int m = idx >> 8, d = idx & 255;
    lk[m * 259 + d] = kvb[(b * MEMN + m) * 512 + d];
    lv[m * 259 + d] = kvb[(b * MEMN + m) * 512 + 256 + d];
  }
  xs[j] = rq[b * 256 + j];
  __syncthreads();

  float v = fmaxf(gemv256(f1T, xs, j) + fb1[j], 0.f);
  __syncthreads(); tb[j] = v; __syncthreads();
  v = gemv256(f2T, tb, j) + fb2[j];
  __syncthreads(); xs[j] = v; __syncthreads();

  for (int hop = 0; hop < 3; ++hop) {
    v = gemv256(wqT, xs, j) + bq[j];
    __syncthreads(); qs[j] = v; __syncthreads();

    const int w = j >> 6, l = j & 63;
    float sc = -1e30f;
    if (l < MEMN) {
      sc = 0.f;
#pragma unroll 16
      for (int d = 0; d < 64; ++d) sc += qs[w * 64 + d] * lk[l * 259 + w * 64 + d];
      sc *= 0.125f;  // 1/sqrt(dk=64)
    }
    float mx = sc;
#pragma unroll
    for (int off = 32; off > 0; off >>= 1) mx = fmaxf(mx, __shfl_xor(mx, off));
    float e = (l < MEMN) ? __expf(sc - mx) : 0.f;
    float sm = e;
#pragma unroll
    for (int off = 32; off > 0; off >>= 1) sm += __shfl_xor(sm, off);
    float a = e / sm;
    __syncthreads(); asc[j] = a; __syncthreads();

    float av = 0.f;
#pragma unroll 10
    for (int m = 0; m < MEMN; ++m) av += asc[w * 64 + m] * lv[m * 259 + w * 64 + l];
    __syncthreads(); avs[j] = av; __syncthreads();

    v = gemv256(woT, avs, j) + bo[j];
    mb[(b * 3 + hop) * 256 + j] = v;
    if (hop < 2) {
      __syncthreads(); ob[j] = v; __syncthreads();
      v = fmaxf(gemv256(f1T, ob, j) + fb1[j], 0.f);
      __syncthreads(); tb[j] = v; __syncthreads();
      v = gemv256(f2T, tb, j) + fb2[j];
      __syncthreads(); xs[j] = v; __syncthreads();
    }
  }
}

// reasoning[b][j] = sum_p relu(t2)[b*9+p][j]  (t2 already relu'd)
__global__ void k_rsum(const float* __restrict__ t2, float* __restrict__ rs)
{
  int gid = blockIdx.x * TPB + threadIdx.x;
  int b = gid / 768, jj = gid - b * 768;
  float acc = 0.f;
#pragma unroll
  for (int p = 0; p < 9; ++p) acc += t2[(b * 9 + p) * 768 + jj];
  rs[b * 768 + jj] = acc;
}

// out[32][100000] = reasoning @ v_w^T. 64 vocab cols per block, K chunked 128.
__global__ __launch_bounds__(256) void k_vocab(const float* __restrict__ rs,
                                               const float* __restrict__ vw,
                                               float* __restrict__ out)
{
  __shared__ float vt[64 * 132];
  __shared__ float rt[32 * 132];
  const int c0 = blockIdx.x * 64;
  const int tx = threadIdx.x & 15, ty = threadIdx.x >> 4;
  float acc[2][4] = {{0.f,0.f,0.f,0.f},{0.f,0.f,0.f,0.f}};

  for (int k0 = 0; k0 < 768; k0 += 128) {
    for (int idx = threadIdx.x; idx < 2048; idx += 256) {
      int r = idx >> 5, q = idx & 31;
      int col = c0 + r;
      float4 v4 = make_float4(0.f, 0.f, 0.f, 0.f);
      if (col < VOC) v4 = ((const float4*)(vw + (size_t)col * 768 + k0))[q];
      *(float4*)&vt[r * 132 + q * 4] = v4;
    }
    for (int idx = threadIdx.x; idx < 1024; idx += 256) {
      int r = idx >> 5, q = idx & 31;
      float4 v4 = ((const float4*)(rs + r * 768 + k0))[q];
      *(float4*)&rt[r * 132 + q * 4] = v4;
    }
    __syncthreads();
#pragma unroll 4
    for (int kk = 0; kk < 128; ++kk) {
      float a0 = rt[(ty * 2 + 0) * 132 + kk];
      float a1 = rt[(ty * 2 + 1) * 132 + kk];
#pragma unroll
      for (int cc = 0; cc < 4; ++cc) {
        float bv_ = vt[(tx + cc * 16) * 132 + kk];
        acc[0][cc] += a0 * bv_;
        acc[1][cc] += a1 * bv_;
      }
    }
    __syncthreads();
  }
#pragma unroll
  for (int rr = 0; rr < 2; ++rr)
#pragma unroll
    for (int cc = 0; cc < 4; ++cc) {
      int c = c0 + tx + cc * 16;
      if (c < VOC) out[(ty * 2 + rr) * VOC + c] = acc[rr][cc];
    }
}

// ---------------------------------------------------------------------------
extern "C" void kernel_launch(void* const* d_in, const int* in_sizes, int n_in,
                              void* d_out, int out_size, void* d_ws, size_t ws_size,
                              hipStream_t stream)
{
  const int*   story = (const int*)d_in[0];
  const int*   query = (const int*)d_in[1];
  const float* embed = (const float*)d_in[2];
  const float* w_ih  = (const float*)d_in[3];
  const float* w_hh  = (const float*)d_in[4];
  const float* b_ih  = (const float*)d_in[5];
  const float* b_hh  = (const float*)d_in[6];
  const float* ft_w1 = (const float*)d_in[7];
  const float* ft_b1 = (const float*)d_in[8];
  const float* ft_w2 = (const float*)d_in[9];
  const float* ft_b2 = (const float*)d_in[10];
  const float* wq    = (const float*)d_in[11];
  const float* bq    = (const float*)d_in[12];
  const float* wk    = (const float*)d_in[13];
  const float* bk    = (const float*)d_in[14];
  const float* wv    = (const float*)d_in[15];
  const float* bv    = (const float*)d_in[16];
  const float* wo    = (const float*)d_in[17];
  const float* bo    = (const float*)d_in[18];
  const float* g_w1  = (const float*)d_in[19];
  const float* g_b1  = (const float*)d_in[20];
  const float* g_w2  = (const float*)d_in[21];
  const float* g_b2  = (const float*)d_in[22];
  const float* v_w   = (const float*)d_in[23];
  float* out = (float*)d_out;
  float* ws  = (float*)d_ws;

  // 1) transposes / biases / seqend indices / counter zero
  k_setup<<<7689, TPB, 0, stream>>>(w_ih, w_hh, wk, wv, wq, wo, ft_w1, ft_w2,
                                    g_w1, g_w2, bk, bv, story, query, ws);
  // 2) fused: GRU chains (blocks 0..81) + gi producer tiles (82..1611)
  k_fused<<<NGRU + NTILE, 1024, 0, stream>>>(
      ws + GI_OFF, w_hh, b_hh, (const int*)(ws + IDX_OFF),
      ws + WTIH_OFF, b_ih, story, query, embed,
      ws + SLOT_OFF, ws + RQ_OFF, (unsigned int*)(ws + CNT_OFF));
  // 3) k/v projections: [1600][512] = slots @ [wk^T|wv^T] + [bk|bv]
  k_gemm<0,128><<<dim3(13, 4), TPB, 0, stream>>>(
      ws + SLOT_OFF, ws + KVT_OFF, ws + BKV_OFF, ws + KVB_OFF, 1600, 512, 256, 0,
      nullptr, nullptr);
  // 4) 3 attention hops + f_t chain
  k_hops<<<NB, TPB, 0, stream>>>(ws + RQ_OFF, ws + KVB_OFF,
                                 ws + WQT_OFF, bq, ws + WOT_OFF, bo,
                                 ws + F1T_OFF, ft_b1, ws + F2T_OFF, ft_b2,
                                 ws + MB_OFF);
  // 5) reasoning layer 1: relu(comb @ g_w1^T + b1), M=288 (32-row tiles)
  k_gemm<2,32><<<dim3(9, 6), TPB, 0, stream>>>(
      nullptr, ws + G1T_OFF, g_b1, ws + T1_OFF, 288, 768, 768, 1,
      ws + MB_OFF, ws + RQ_OFF);
  // 6) reasoning layer 2: relu(t1 @ g_w2^T + b2)
  k_gemm<0,32><<<dim3(9, 6), TPB, 0, stream>>>(
      ws + T1_OFF, ws + G2T_OFF, g_b2, ws + T2_OFF, 288, 768, 768, 1,
      nullptr, nullptr);
  // 7) sum over 9 pairs
  k_rsum<<<96, TPB, 0, stream>>>(ws + T2_OFF, ws + RS_OFF);
  // 8) logits = reasoning @ v_w^T
  k_vocab<<<(VOC + 63) / 64, TPB, 0, stream>>>(ws + RS_OFF, v_w, out);
}